// Round 1
// baseline (19.786 us; speedup 1.0000x reference)
//
#include <hip/hip_runtime.h>

#define NN 1024
#define BB 16
#define NTY 3

__global__ __launch_bounds__(256) void eam_rows(
    const int* __restrict__ types, const int* __restrict__ n_atoms,
    const float* __restrict__ distances,
    const float* __restrict__ phi_params, const float* __restrict__ rho_params,
    const float* __restrict__ emb_params, float* __restrict__ row_e)
{
    __shared__ int4  s_types4[NN / 4];
    __shared__ float4 s_tbl[NTY * NTY];

    const int tid = threadIdx.x;
    const int b = blockIdx.y;
    const int rowBase = blockIdx.x * 8;

    // stage this batch's types row into LDS (vectorized)
    s_types4[tid] = ((const int4*)(types + b * NN))[tid];

    // build the 3x3 pair-type parameter table:
    // phi = p0*exp(-p1*(d-p2)) = (p0*e^{p1 p2}) * 2^{(-p1*log2e)*d}
    if (tid < NTY * NTY) {
        const int ti = tid / NTY, tj = tid % NTY;
        const int lo = min(ti, tj), hi = max(ti, tj);
        const int pt = lo * (2 * NTY - lo + 1) / 2 + (hi - lo);
        const float p0 = phi_params[pt * 3 + 0];
        const float p1 = phi_params[pt * 3 + 1];
        const float p2 = phi_params[pt * 3 + 2];
        const float r0 = rho_params[pt * 3 + 0];
        const float r1 = rho_params[pt * 3 + 1];
        const float r2 = rho_params[pt * 3 + 2];
        const float LOG2E = 1.44269504088896f;
        s_tbl[tid] = make_float4(p0 * __expf(p1 * p2), -p1 * LOG2E,
                                 r0 * __expf(r1 * r2), -r1 * LOG2E);
    }
    __syncthreads();

    const int lane = tid & 63;
    const int wave = tid >> 6;
    const int na = n_atoms[b];
    const int* s_types = (const int*)s_types4;

#pragma unroll
    for (int rr = 0; rr < 2; ++rr) {
        const int i = rowBase + wave * 2 + rr;
        if (i < na) {
            const int ti = s_types[i];
            const float4* drow =
                (const float4*)(distances + ((size_t)(b * NN + i)) * NN);
            float sph = 0.f, srh = 0.f;
#pragma unroll
            for (int pass = 0; pass < 4; ++pass) {
                const int c4 = pass * 64 + lane;      // float4 index in row
                const float4 d4 = drow[c4];
                const int4 tj4 = s_types4[c4];
                const int jb = c4 * 4;

#define EAM_EL(E, DD, TT)                                                     \
                {                                                             \
                    const float4 prm = s_tbl[ti * NTY + (TT)];                \
                    float phi = prm.x * __builtin_amdgcn_exp2f(prm.y * (DD)); \
                    float rho = prm.z * __builtin_amdgcn_exp2f(prm.w * (DD)); \
                    const int j = jb + (E);                                   \
                    if (j >= na || j == i) { phi = 0.f; rho = 0.f; }          \
                    sph += phi;                                               \
                    srh += rho * rho;                                         \
                }
                EAM_EL(0, d4.x, tj4.x)
                EAM_EL(1, d4.y, tj4.y)
                EAM_EL(2, d4.z, tj4.z)
                EAM_EL(3, d4.w, tj4.w)
#undef EAM_EL
            }
            // wave-level butterfly reduce (64 lanes)
#pragma unroll
            for (int o = 32; o > 0; o >>= 1) {
                sph += __shfl_xor(sph, o, 64);
                srh += __shfl_xor(srh, o, 64);
            }
            if (lane == 0) {
                const float A   = emb_params[ti * 2 + 0];
                const float off = emb_params[ti * 2 + 1];
                row_e[b * NN + i] =
                    sph + (-A * sqrtf(fmaxf(srh, 1e-30f)) + off);
            }
        } else {
            if (lane == 0) row_e[b * NN + i] = 0.f;
        }
    }
}

__global__ __launch_bounds__(256) void eam_reduce(
    const float* __restrict__ row_e, const int* __restrict__ n_atoms,
    float* __restrict__ out)
{
    const int b = blockIdx.x;
    const int tid = threadIdx.x;
    const float4 v = ((const float4*)(row_e + b * NN))[tid];
    float s = v.x + v.y + v.z + v.w;
#pragma unroll
    for (int o = 32; o > 0; o >>= 1) s += __shfl_xor(s, o, 64);

    __shared__ float wsum[4];
    const int lane = tid & 63, wave = tid >> 6;
    if (lane == 0) wsum[wave] = s;
    __syncthreads();
    if (tid == 0) {
        const float t = wsum[0] + wsum[1] + wsum[2] + wsum[3];
        out[b] = t / (float)n_atoms[b];
    }
}

extern "C" void kernel_launch(void* const* d_in, const int* in_sizes, int n_in,
                              void* d_out, int out_size, void* d_ws, size_t ws_size,
                              hipStream_t stream) {
    const int*   types      = (const int*)d_in[0];
    const int*   n_atoms    = (const int*)d_in[1];
    const float* distances  = (const float*)d_in[2];
    // d_in[3] = pair_types: recomputed on the fly, not read (saves 64 MB)
    const float* phi_params = (const float*)d_in[4];
    const float* rho_params = (const float*)d_in[5];
    const float* emb_params = (const float*)d_in[6];

    float* row_e = (float*)d_ws;  // B*N floats = 64 KB

    eam_rows<<<dim3(NN / 8, BB), 256, 0, stream>>>(
        types, n_atoms, distances, phi_params, rho_params, emb_params, row_e);
    eam_reduce<<<BB, 256, 0, stream>>>(row_e, n_atoms, (float*)d_out);
}